// Round 2
// baseline (1232.376 us; speedup 1.0000x reference)
//
#include <hip/hip_runtime.h>
#include <hip/hip_bf16.h>
#include <cstddef>

#define BB 1024
#define TT 4096
#define LL 30
#define HH 32
#define K_SETS 4
// P = 2, DT = 1.0

// ---- fast branch-free tanh (encoder + epilogue): abs err ~1e-7 ----
__device__ __forceinline__ float tanh_fast(float x) {
    float t = __builtin_amdgcn_exp2f(x * 2.8853900817779268f);
    float r = __builtin_amdgcn_rcpf(t + 1.0f);
    return fmaf(-2.0f, r, 1.0f);
}

// ---- DPP add step (full-rate VALU cross-lane, no LDS) ----
template <int CTRL>
__device__ __forceinline__ float dpp_add_f(float x) {
    int xi = __float_as_int(x);
    int yi = __builtin_amdgcn_update_dpp(0, xi, CTRL, 0xF, 0xF, true);
    return x + __int_as_float(yi);
}

// sum across each row of 16 lanes; every lane ends with the sum
__device__ __forceinline__ float red16(float x) {
    x = dpp_add_f<0xB1>(x);   // quad_perm xor1
    x = dpp_add_f<0x4E>(x);   // quad_perm xor2
    x = dpp_add_f<0x141>(x);  // row_half_mirror
    x = dpp_add_f<0x140>(x);  // row_mirror
    return x;
}

// Kernel 1: encoder + sequential Euler scan.
// 16 lanes per chain, 4 chain-groups per wave, K_SETS=4 independent chain-sets
// per wave interleaved in the instruction stream to fill latency stalls.
// 64 blocks x 64 threads -> 16 chains/wave x 64 waves = 1024 chains.
__global__ __launch_bounds__(64) void ode_scan_kernel(
    const float* __restrict__ x,
    const float* __restrict__ ew1, const float* __restrict__ eb1,
    const float* __restrict__ ew2, const float* __restrict__ eb2,
    const float* __restrict__ fw1, const float* __restrict__ fb1,
    const float* __restrict__ fw2, const float* __restrict__ fb2,
    float* __restrict__ zout)
{
    const int tid = threadIdx.x;
    const int g   = tid & 15;                    // lane within 16-lane group
    const int grp = tid >> 4;                    // chain group within wave
    const int j0  = g;                           // hidden unit A
    const int j1  = g + 16;                      // hidden unit B

    // ---- f-MLP weights, prescaled/folded to shorten the per-step chain ----
    // tanh(a) = 1 - 2*rcp(exp2(a*2log2e)+1); fold 2log2e into W1,b1.
    const float KE   = 2.8853900817779268f;
    const float w10  = fw1[j0] * KE,  w10b = fw1[HH + j0] * KE;
    const float w11  = fw1[j1] * KE,  w11b = fw1[HH + j1] * KE;
    const float b10  = fb1[j0] * KE,  b11  = fb1[j1] * KE;
    // h*w2 = (1-2r)*w2 = w2 + r*(-2w2); fold constants + b2/16 into per-lane base.
    const float w200 = fw2[j0 * 2 + 0],  w201 = fw2[j0 * 2 + 1];
    const float w210 = fw2[j1 * 2 + 0],  w211 = fw2[j1 * 2 + 1];
    const float base0 = w200 + w210 + fb2[0] * 0.0625f;
    const float base1 = w201 + w211 + fb2[1] * 0.0625f;
    const float n200 = -2.0f * w200, n201 = -2.0f * w201;
    const float n210 = -2.0f * w210, n211 = -2.0f * w211;

    float z1[K_SETS], z2[K_SETS];
    float* zb[K_SETS];

    // ---------------- encoder per chain-set: z0 = tanh(x@ew1+eb1)@ew2+eb2
    #pragma unroll
    for (int s = 0; s < K_SETS; ++s) {
        const int b = blockIdx.x * (4 * K_SETS) + s * 4 + grp;
        float s0 = eb1[j0], s1 = eb1[j1];
        const float* xb = x + (size_t)b * TT;
        #pragma unroll
        for (int l = 0; l < LL; ++l) {
            float xv = xb[l];
            s0 = fmaf(xv, ew1[l * HH + j0], s0);
            s1 = fmaf(xv, ew1[l * HH + j1], s1);
        }
        float h0 = tanh_fast(s0), h1 = tanh_fast(s1);
        float p0 = fmaf(h1, ew2[j1 * 2 + 0], h0 * ew2[j0 * 2 + 0]);
        float p1 = fmaf(h1, ew2[j1 * 2 + 1], h0 * ew2[j0 * 2 + 1]);
        p0 = red16(p0);
        p1 = red16(p1);
        z1[s] = p0 + eb2[0];
        z2[s] = p1 + eb2[1];
        zb[s] = zout + (size_t)b * TT * 2;
    }
    if (g == 0) {
        #pragma unroll
        for (int s = 0; s < K_SETS; ++s) {
            float2 v; v.x = z1[s]; v.y = z2[s];
            *(float2*)zb[s] = v;
        }
    }

    // ---------------- sequential Euler scan: 4 independent sets interleaved
    for (int t = 1; t < TT; ++t) {
        #pragma unroll
        for (int s = 0; s < K_SETS; ++s) {
            float a0 = fmaf(z2[s], w10b, fmaf(z1[s], w10, b10));
            float a1 = fmaf(z2[s], w11b, fmaf(z1[s], w11, b11));
            float e0 = __builtin_amdgcn_exp2f(a0);
            float e1 = __builtin_amdgcn_exp2f(a1);
            float r0 = __builtin_amdgcn_rcpf(e0 + 1.0f);
            float r1 = __builtin_amdgcn_rcpf(e1 + 1.0f);
            float q0 = fmaf(r1, n210, fmaf(r0, n200, base0));
            float q1 = fmaf(r1, n211, fmaf(r0, n201, base1));
            q0 = red16(q0);
            q1 = red16(q1);
            z1[s] += q0;   // DT = 1.0, b2 folded into base
            z2[s] += q1;
        }
        if (g == 0) {
            #pragma unroll
            for (int s = 0; s < K_SETS; ++s) {
                float2 v; v.x = z1[s]; v.y = z2[s];
                *(float2*)(zb[s] + t * 2) = v;
            }
        }
    }
}

// Kernel 2: streaming epilogue. Reads z (out2) + phi, writes a (out1) and xhat (out0).
__global__ __launch_bounds__(256) void finalize_kernel(
    const float* __restrict__ phi, const float* __restrict__ z,
    float* __restrict__ xhat, float* __restrict__ a)
{
    const int idx = blockIdx.x * blockDim.x + threadIdx.x;
    const int pos = idx * 2;                    // position pair (same b; t0 even)
    const int t0  = pos & (TT - 1);

    float4 zv = *(const float4*)(z   + (size_t)pos * 2);
    float4 pv = *(const float4*)(phi + (size_t)pos * 2);

    float k1a = tanh_fast(zv.x), k2a = tanh_fast(zv.y);
    float k1b = tanh_fast(zv.z), k2b = tanh_fast(zv.w);

    float a1a = k1a * (1.0f - k2a), a2a = k2a;
    float a1b = k1b * (1.0f - k2b), a2b = k2b;

    float4 av; av.x = a1a; av.y = a2a; av.z = a1b; av.w = a2b;
    *(float4*)(a + (size_t)pos * 2) = av;

    float x0 = (t0 >= 2)     ? fmaf(a2a, pv.y, a1a * pv.x) : 0.0f;
    float x1 = (t0 + 1 >= 2) ? fmaf(a2b, pv.w, a1b * pv.z) : 0.0f;
    float2 xv; xv.x = x0; xv.y = x1;
    *(float2*)(xhat + pos) = xv;
}

extern "C" void kernel_launch(void* const* d_in, const int* in_sizes, int n_in,
                              void* d_out, int out_size, void* d_ws, size_t ws_size,
                              hipStream_t stream) {
    const float* x    = (const float*)d_in[0];
    const float* phi  = (const float*)d_in[1];
    const float* ew1  = (const float*)d_in[2];
    const float* eb1  = (const float*)d_in[3];
    const float* ew2  = (const float*)d_in[4];
    const float* eb2  = (const float*)d_in[5];
    const float* fw1  = (const float*)d_in[6];
    const float* fb1  = (const float*)d_in[7];
    const float* fw2  = (const float*)d_in[8];
    const float* fb2  = (const float*)d_in[9];

    float* out  = (float*)d_out;
    float* xhat = out;                          // (B, T)
    float* a    = out + (size_t)BB * TT;        // (B, T, 2)
    float* z    = out + (size_t)BB * TT * 3;    // (B, T, 2)

    // 64 blocks x 64 threads: 1 wave/block, 16 chains/wave (4 groups x 4 sets)
    ode_scan_kernel<<<BB / (4 * K_SETS), 64, 0, stream>>>(x, ew1, eb1, ew2, eb2,
                                                          fw1, fb1, fw2, fb2, z);

    const int total_pairs = (BB * TT) / 2;
    finalize_kernel<<<total_pairs / 256, 256, 0, stream>>>(phi, z, xhat, a);
}

// Round 3
// 314.219 us; speedup vs baseline: 3.9220x; 3.9220x over previous
//
#include <hip/hip_runtime.h>
#include <hip/hip_bf16.h>
#include <cstddef>

#define BB 1024
#define TT 4096
#define LL 30
#define HH 32
// P = 2, DT = 1.0

// ---- fast branch-free tanh (encoder + epilogue): abs err ~1e-7 ----
__device__ __forceinline__ float tanh_fast(float x) {
    float t = __builtin_amdgcn_exp2f(x * 2.8853900817779268f);
    float r = __builtin_amdgcn_rcpf(t + 1.0f);
    return fmaf(-2.0f, r, 1.0f);
}

// ---- DPP add step (full-rate VALU cross-lane, no LDS) ----
template <int CTRL>
__device__ __forceinline__ float dpp_add_f(float x) {
    int xi = __float_as_int(x);
    int yi = __builtin_amdgcn_update_dpp(0, xi, CTRL, 0xF, 0xF, true);
    return x + __int_as_float(yi);
}

// two independent 16-lane reductions, trees interleaved to hide DPP hazards
__device__ __forceinline__ void red16x2(float& x, float& y) {
    x = dpp_add_f<0xB1>(x);   y = dpp_add_f<0xB1>(y);    // quad_perm xor1
    x = dpp_add_f<0x4E>(x);   y = dpp_add_f<0x4E>(y);    // quad_perm xor2
    x = dpp_add_f<0x141>(x);  y = dpp_add_f<0x141>(y);   // row_half_mirror
    x = dpp_add_f<0x140>(x);  y = dpp_add_f<0x140>(y);   // row_mirror
    return;
}

// Kernel 1: encoder + sequential Euler scan.
// 16 lanes per chain, 4 chains per wave, 256 waves (1 per CU).
// t-loop unrolled by 16: per-step capture via branch-free selects,
// one fully-coalesced 128B/group burst store every 16 steps.
__global__ __launch_bounds__(64) void ode_scan_kernel(
    const float* __restrict__ x,
    const float* __restrict__ ew1, const float* __restrict__ eb1,
    const float* __restrict__ ew2, const float* __restrict__ eb2,
    const float* __restrict__ fw1, const float* __restrict__ fb1,
    const float* __restrict__ fw2, const float* __restrict__ fb2,
    float* __restrict__ zout)
{
    const int tid = threadIdx.x;
    const int g   = tid & 15;                    // lane within 16-lane group
    const int b   = blockIdx.x * 4 + (tid >> 4); // batch chain
    const int j0  = g;                           // hidden unit A
    const int j1  = g + 16;                      // hidden unit B

    // ---- f-MLP weights, prescaled/folded (same math as round 2, absmax 4.0) ----
    const float KE   = 2.8853900817779268f;      // 2*log2(e)
    const float w10  = fw1[j0] * KE,  w10b = fw1[HH + j0] * KE;
    const float w11  = fw1[j1] * KE,  w11b = fw1[HH + j1] * KE;
    const float b10  = fb1[j0] * KE,  b11  = fb1[j1] * KE;
    const float w200 = fw2[j0 * 2 + 0],  w201 = fw2[j0 * 2 + 1];
    const float w210 = fw2[j1 * 2 + 0],  w211 = fw2[j1 * 2 + 1];
    const float base0 = w200 + w210 + fb2[0] * 0.0625f;  // b2/16: red16 sums 16 copies
    const float base1 = w201 + w211 + fb2[1] * 0.0625f;
    const float n200 = -2.0f * w200, n201 = -2.0f * w201;
    const float n210 = -2.0f * w210, n211 = -2.0f * w211;

    // ---------------- encoder: z0 = tanh(x[:, :30] @ ew1 + eb1) @ ew2 + eb2
    float z1, z2;
    {
        float s0 = eb1[j0], s1 = eb1[j1];
        const float* xb = x + (size_t)b * TT;
        #pragma unroll
        for (int l = 0; l < LL; ++l) {
            float xv = xb[l];
            s0 = fmaf(xv, ew1[l * HH + j0], s0);
            s1 = fmaf(xv, ew1[l * HH + j1], s1);
        }
        float h0 = tanh_fast(s0), h1 = tanh_fast(s1);
        float p0 = fmaf(h1, ew2[j1 * 2 + 0], h0 * ew2[j0 * 2 + 0]);
        float p1 = fmaf(h1, ew2[j1 * 2 + 1], h0 * ew2[j0 * 2 + 1]);
        red16x2(p0, p1);
        z1 = p0 + eb2[0];
        z2 = p1 + eb2[1];
    }

    // one Euler step (DT=1, b2 folded into base via red16)
    #define STEP() do {                                          \
        float a0 = fmaf(z2, w10b, fmaf(z1, w10, b10));           \
        float a1 = fmaf(z2, w11b, fmaf(z1, w11, b11));           \
        float e0 = __builtin_amdgcn_exp2f(a0);                   \
        float e1 = __builtin_amdgcn_exp2f(a1);                   \
        float r0 = __builtin_amdgcn_rcpf(e0 + 1.0f);             \
        float r1 = __builtin_amdgcn_rcpf(e1 + 1.0f);             \
        float q0 = fmaf(r1, n210, fmaf(r0, n200, base0));        \
        float q1 = fmaf(r1, n211, fmaf(r0, n201, base1));        \
        red16x2(q0, q1);                                         \
        z1 += q0; z2 += q1;                                      \
    } while (0)

    // history regs: lane g holds timeline entry (16*burst + g).
    // init h = z0 covers the g==0 slot of burst 0.
    float h1 = z1, h2 = z2;
    float* zp = zout + (size_t)b * TT * 2 + g * 2;  // lane g's slot in burst 0

    // ---- prologue burst: entries 1..15 (15 steps), captures at g==1..15
    #pragma unroll
    for (int k = 1; k < 16; ++k) {
        STEP();
        h1 = (g == k) ? z1 : h1;
        h2 = (g == k) ? z2 : h2;
    }
    { float2 v; v.x = h1; v.y = h2; *(float2*)zp = v; zp += 32; }

    // ---- main loop: 255 bursts x 16 steps
    for (int bb = 1; bb < 256; ++bb) {
        #pragma unroll
        for (int k = 0; k < 16; ++k) {
            STEP();
            h1 = (g == k) ? z1 : h1;
            h2 = (g == k) ? z2 : h2;
        }
        float2 v; v.x = h1; v.y = h2; *(float2*)zp = v; zp += 32;
    }
    #undef STEP
}

// Kernel 2: streaming epilogue. Reads z (out2) + phi, writes a (out1) and xhat (out0).
__global__ __launch_bounds__(256) void finalize_kernel(
    const float* __restrict__ phi, const float* __restrict__ z,
    float* __restrict__ xhat, float* __restrict__ a)
{
    const int idx = blockIdx.x * blockDim.x + threadIdx.x;
    const int pos = idx * 2;                    // position pair (same b; t0 even)
    const int t0  = pos & (TT - 1);

    float4 zv = *(const float4*)(z   + (size_t)pos * 2);
    float4 pv = *(const float4*)(phi + (size_t)pos * 2);

    float k1a = tanh_fast(zv.x), k2a = tanh_fast(zv.y);
    float k1b = tanh_fast(zv.z), k2b = tanh_fast(zv.w);

    float a1a = k1a * (1.0f - k2a), a2a = k2a;
    float a1b = k1b * (1.0f - k2b), a2b = k2b;

    float4 av; av.x = a1a; av.y = a2a; av.z = a1b; av.w = a2b;
    *(float4*)(a + (size_t)pos * 2) = av;

    float x0 = (t0 >= 2)     ? fmaf(a2a, pv.y, a1a * pv.x) : 0.0f;
    float x1 = (t0 + 1 >= 2) ? fmaf(a2b, pv.w, a1b * pv.z) : 0.0f;
    float2 xv; xv.x = x0; xv.y = x1;
    *(float2*)(xhat + pos) = xv;
}

extern "C" void kernel_launch(void* const* d_in, const int* in_sizes, int n_in,
                              void* d_out, int out_size, void* d_ws, size_t ws_size,
                              hipStream_t stream) {
    const float* x    = (const float*)d_in[0];
    const float* phi  = (const float*)d_in[1];
    const float* ew1  = (const float*)d_in[2];
    const float* eb1  = (const float*)d_in[3];
    const float* ew2  = (const float*)d_in[4];
    const float* eb2  = (const float*)d_in[5];
    const float* fw1  = (const float*)d_in[6];
    const float* fb1  = (const float*)d_in[7];
    const float* fw2  = (const float*)d_in[8];
    const float* fb2  = (const float*)d_in[9];

    float* out  = (float*)d_out;
    float* xhat = out;                          // (B, T)
    float* a    = out + (size_t)BB * TT;        // (B, T, 2)
    float* z    = out + (size_t)BB * TT * 3;    // (B, T, 2)

    // 256 blocks x 64 threads: 1 wave/block, 1 block/CU, 4 chains/wave
    ode_scan_kernel<<<256, 64, 0, stream>>>(x, ew1, eb1, ew2, eb2,
                                            fw1, fb1, fw2, fb2, z);

    const int total_pairs = (BB * TT) / 2;
    finalize_kernel<<<total_pairs / 256, 256, 0, stream>>>(phi, z, xhat, a);
}